// Round 12
// baseline (370.322 us; speedup 1.0000x reference)
//
#include <hip/hip_runtime.h>
#include <math.h>

#define NB 32
#define NT 1024
#define ND 256
#define NROWS (NB*NT)
#define MAXE 64

typedef __attribute__((ext_vector_type(8))) short bf16x8;
typedef __attribute__((ext_vector_type(4))) float f32x4;
typedef unsigned short ushort_t;
typedef unsigned long long u64;

__device__ inline ushort_t f2bf_rn(float f){
  unsigned u = __float_as_uint(f);
  unsigned r = u + 0x7fffu + ((u >> 16) & 1u);
  return (ushort_t)(r >> 16);
}
__device__ inline float bf2f(ushort_t h){
  return __uint_as_float(((unsigned)h) << 16);
}

// async global->LDS, 16B per lane, dest = ldsbase + lane*16
__device__ inline void gld16(const ushort_t* g, ushort_t* l){
  __builtin_amdgcn_global_load_lds(
      (const __attribute__((address_space(1))) unsigned int*)(g),
      (__attribute__((address_space(3))) unsigned int*)(l),
      16, 0, 0);
}

// orderable key for fp32 (monotone map to unsigned)
__device__ inline unsigned okey(float v){
  unsigned u = __float_as_uint(v);
  return u ^ ((unsigned)((int)u >> 31) | 0x80000000u);
}
// u32 sorted-pair insert / merge (single v_max_u32-class ops)
__device__ inline void ins2u(unsigned &e0, unsigned &e1, unsigned e){
  unsigned mn = e0 > e ? e : e0;
  e0 = e0 > e ? e0 : e;
  e1 = e1 > mn ? e1 : mn;
}
__device__ inline void merge2u(unsigned &e0, unsigned &e1, unsigned r0, unsigned r1){
  unsigned first = e0 > r0 ? e0 : r0;
  unsigned mn    = e0 > r0 ? r0 : e0;
  unsigned mx1   = e1 > r1 ? e1 : r1;
  e0 = first;
  e1 = mn > mx1 ? mn : mx1;
}

// ---------------- K1: row L2-normalize + bf16 split (xh + xl = xn) ----------
__global__ __launch_bounds__(256) void k_norm(const float* __restrict__ x,
                                              float* __restrict__ xn,
                                              ushort_t* __restrict__ xh,
                                              ushort_t* __restrict__ xl){
  int row = blockIdx.x;
  int t = threadIdx.x;
  size_t base = (size_t)row*ND;
  float v = x[base + t];
  float ss = v*v;
  #pragma unroll
  for (int off=32; off; off>>=1) ss += __shfl_xor(ss, off);
  __shared__ float sred[4];
  if ((t & 63) == 0) sred[t>>6] = ss;
  __syncthreads();
  float tot = sred[0] + sred[1] + sred[2] + sred[3];
  float nrm = fmaxf(sqrtf(tot), 1e-12f);
  float res = v / nrm;
  xn[base + t] = res;
  ushort_t hb = f2bf_rn(res);
  float lres = res - bf2f(hb);
  xh[base + t] = hb;
  xl[base + t] = f2bf_rn(lres);
}

// ---------------- Kw: split W into bf16 high/low streams --------------------
__global__ __launch_bounds__(256) void k_wsplit(const float* __restrict__ W0,
                                                const float* __restrict__ W1,
                                                ushort_t* __restrict__ Wh0, ushort_t* __restrict__ Wl0,
                                                ushort_t* __restrict__ Wh1, ushort_t* __restrict__ Wl1){
  int idx = blockIdx.x*256 + threadIdx.x;    // 65536
  float w0 = W0[idx]; ushort_t h0 = f2bf_rn(w0);
  Wh0[idx] = h0; Wl0[idx] = f2bf_rn(w0 - bf2f(h0));
  float w1 = W1[idx]; ushort_t h1 = f2bf_rn(w1);
  Wh1[idx] = h1; Wl1[idx] = f2bf_rn(w1 - bf2f(h1));
}

// ---------------- K2: MFMA sim GEMM, symmetric, FUSED strip-top-2 -----------
__global__ __launch_bounds__(256) void k_sim(const ushort_t* __restrict__ xh,
                                             const ushort_t* __restrict__ xl,
                                             unsigned* __restrict__ cand){
  __shared__ __align__(16) ushort_t Ahs[128*64];
  __shared__ __align__(16) ushort_t Als[128*64];
  __shared__ __align__(16) ushort_t Bhs[128*64];
  __shared__ __align__(16) ushort_t Bls[128*64];

  // XCD swizzle: 1152 blocks = 144 contiguous tiles (4 batches) per XCD
  int blk0 = blockIdx.x;
  int blk = (blk0 & 7)*144 + (blk0 >> 3);

  int b = blk / 36;
  int tt = blk % 36;
  int ti = 0, rem = tt;
  while (rem >= 8 - ti){ rem -= 8 - ti; ti++; }
  int tj = ti + rem;                    // ti <= tj
  int i0 = ti*128, j0 = tj*128;

  int t = threadIdx.x;
  int lane = t & 63, wave = t >> 6;
  int wy = wave >> 1, wx = wave & 1;
  int c = lane & 15, q = lane >> 4;
  int lrow = lane >> 3;                 // 0..7 (row within 8-row stage block)
  int sc   = (lane & 7) ^ lrow;         // pre-swizzled source chunk

  f32x4 acc[4][4];
  #pragma unroll
  for (int bi=0;bi<4;bi++)
    #pragma unroll
    for (int bj=0;bj<4;bj++) acc[bi][bj] = {0.f,0.f,0.f,0.f};

  size_t rowbA = (size_t)(b*NT + i0);
  size_t rowbB = (size_t)(b*NT + j0);
  const ushort_t* Agh = xh + rowbA*ND;
  const ushort_t* Agl = xl + rowbA*ND;
  const ushort_t* Bgh = xh + rowbB*ND;
  const ushort_t* Bgl = xl + rowbB*ND;

  for (int kc=0; kc<4; kc++){
    __syncthreads();                    // previous tile fully consumed
    int koff = kc*64;
    #pragma unroll
    for (int inst=0; inst<4; inst++){
      int r0 = wave*32 + inst*8;        // wave-uniform row base
      size_t go = (size_t)(r0 + lrow)*ND + koff + sc*8;
      gld16(Agh + go, &Ahs[r0*64]);
      gld16(Agl + go, &Als[r0*64]);
      gld16(Bgh + go, &Bhs[r0*64]);
      gld16(Bgl + go, &Bls[r0*64]);
    }
    __syncthreads();                    // drains vmcnt before reads

    #pragma unroll
    for (int ks=0; ks<2; ks++){
      bf16x8 ah[4], al[4], bh[4], bl[4];
      int slot = (ks*4 + q) ^ (c & 7);
      #pragma unroll
      for (int bi=0;bi<4;bi++){
        int row = wy*64 + bi*16 + c;
        ah[bi] = *(const bf16x8*)&Ahs[row*64 + slot*8];
        al[bi] = *(const bf16x8*)&Als[row*64 + slot*8];
      }
      #pragma unroll
      for (int bj=0;bj<4;bj++){
        int row = wx*64 + bj*16 + c;
        bh[bj] = *(const bf16x8*)&Bhs[row*64 + slot*8];
        bl[bj] = *(const bf16x8*)&Bls[row*64 + slot*8];
      }
      #pragma unroll
      for (int bi=0;bi<4;bi++)
        #pragma unroll
        for (int bj=0;bj<4;bj++){
          acc[bi][bj] = __builtin_amdgcn_mfma_f32_16x16x32_bf16(ah[bi], bh[bj], acc[bi][bj], 0, 0, 0);
          acc[bi][bj] = __builtin_amdgcn_mfma_f32_16x16x32_bf16(al[bi], bh[bj], acc[bi][bj], 0, 0, 0);
          acc[bi][bj] = __builtin_amdgcn_mfma_f32_16x16x32_bf16(ah[bi], bl[bj], acc[bi][bj], 0, 0, 0);
        }
    }
  }

  const unsigned KMASK = 0xFFFFFC00u;
  size_t bbase = (size_t)b*NT;
  // epilogue A: direct per-row strip top-2.
  #pragma unroll
  for (int bi=0;bi<4;bi++){
    #pragma unroll
    for (int reg=0;reg<4;reg++){
      int row_l = i0 + wy*64 + bi*16 + q*4 + reg;
      unsigned e0 = 0, e1 = 0;
      #pragma unroll
      for (int bj=0;bj<4;bj++){
        int col_l = j0 + wx*64 + bj*16 + c;
        unsigned e = (okey(acc[bi][bj][reg]) & KMASK) | (unsigned)col_l;
        if (col_l == row_l) e = 0;      // diag suppressed (only diag tiles)
        ins2u(e0, e1, e);
      }
      #pragma unroll
      for (int st=1; st<16; st<<=1)
        merge2u(e0, e1, __shfl_xor(e0, st), __shfl_xor(e1, st));
      if (c == 0){
        u64 pk = ((u64)e1 << 32) | e0;
        *(u64*)&cand[(bbase + row_l)*32 + (size_t)(tj*4 + wx*2)] = pk;
      }
    }
  }
  // epilogue B: mirrored per-column strip top-2 (rows of tile tj, strip ti)
  if (ti != tj){
    #pragma unroll
    for (int bj=0;bj<4;bj++){
      int mrow = j0 + wx*64 + bj*16 + c;   // mirror row (= column of tile)
      unsigned e0 = 0, e1 = 0;
      #pragma unroll
      for (int bi=0;bi<4;bi++)
        #pragma unroll
        for (int reg=0;reg<4;reg++){
          int mcol = i0 + wy*64 + bi*16 + q*4 + reg;  // mirror col
          unsigned e = (okey(acc[bi][bj][reg]) & KMASK) | (unsigned)mcol;
          ins2u(e0, e1, e);
        }
      #pragma unroll
      for (int st=16; st<64; st<<=1)
        merge2u(e0, e1, __shfl_xor(e0, st), __shfl_xor(e1, st));
      if (q == 0){
        u64 pk = ((u64)e1 << 32) | e0;
        *(u64*)&cand[(bbase + mrow)*32 + (size_t)(ti*4 + wy*2)] = pk;
      }
    }
  }
}

// ---------------- K2b: reduce 32 strip-candidates -> top-4 cols per row -----
__global__ __launch_bounds__(256) void k_topred(const unsigned* __restrict__ cand,
                                                int4* __restrict__ cand4){
  int row = blockIdx.x*256 + threadIdx.x;   // 32768 rows
  const unsigned* cr = cand + (size_t)row*32;
  unsigned L0=0,L1=0,L2=0,L3=0;
  #pragma unroll
  for (int k=0;k<32;k++){
    unsigned e = cr[k];
    if (e > L0){ L3=L2; L2=L1; L1=L0; L0=e; }
    else if (e > L1){ L3=L2; L2=L1; L1=e; }
    else if (e > L2){ L3=L2; L2=e; }
    else if (e > L3){ L3=e; }
  }
  cand4[row] = make_int4((int)(L0 & 1023u), (int)(L1 & 1023u),
                         (int)(L2 & 1023u), (int)(L3 & 1023u));
}

// ---------------- K3b: fp64-exact refine of 4 candidates -> top-2 -----------
__global__ __launch_bounds__(64) void k_refine4(const float* __restrict__ xn,
                                                const int4* __restrict__ cand4,
                                                int2* __restrict__ top2){
  int row = blockIdx.x; int b = row >> 10, i = row & 1023;
  int l = threadIdx.x;
  const float* Xb = xn + (size_t)b*NT*ND;
  float4 xi = *(const float4*)&Xb[(size_t)i*ND + l*4];
  int4 cd = cand4[row];
  int cands[4] = {cd.x, cd.y, cd.z, cd.w};
  double bv1=-1e30, bv2=-1e30; int bi1=0x7fffffff, bi2=0x7fffffff;
  #pragma unroll
  for (int cq=0;cq<4;cq++){
    int j = cands[cq];
    float4 xj = *(const float4*)&Xb[(size_t)j*ND + l*4];
    double p = (double)xi.x*xj.x + (double)xi.y*xj.y
             + (double)xi.z*xj.z + (double)xi.w*xj.w;
    #pragma unroll
    for (int off=32; off; off>>=1) p += __shfl_xor(p, off);
    if (p > bv1 || (p == bv1 && j < bi1)) { bv2=bv1; bi2=bi1; bv1=p; bi1=j; }
    else if (p > bv2 || (p == bv2 && j < bi2)) { bv2=p; bi2=j; }
  }
  if (l == 0) top2[row] = make_int2(bi1, bi2);
}

// ---------------- K4: scatter symmetric ext edges into bitmask --------------
__global__ __launch_bounds__(256) void k_scatter(const int2* __restrict__ top2,
                                                 unsigned* __restrict__ ext){
  int row = blockIdx.x*256 + threadIdx.x;
  int b = row >> 10, i = row & 1023;
  int2 tp = top2[row];
  unsigned* eb = ext + (size_t)b*NT*32;
  int j1 = tp.x, j2 = tp.y;
  atomicOr(&eb[(size_t)i*32 + (j1>>5)], 1u << (j1&31));
  atomicOr(&eb[(size_t)j1*32 + (i>>5)], 1u << (i&31));
  atomicOr(&eb[(size_t)i*32 + (j2>>5)], 1u << (j2&31));
  atomicOr(&eb[(size_t)j2*32 + (i>>5)], 1u << (i&31));
}

// ---------------- K5: enumerate edge union, recompute sim values, row sums --
__global__ __launch_bounds__(64) void k_edges(const float* __restrict__ xn,
                                              const unsigned* __restrict__ ext,
                                              int* __restrict__ eidx,
                                              float* __restrict__ eval_,
                                              float* __restrict__ rs,
                                              int* __restrict__ ecnt){
  int row = blockIdx.x; int b = row >> 10, i = row & 1023;
  int l = threadIdx.x;
  const float* Xb = xn + (size_t)b*NT*ND;
  float4 xi = *(const float4*)&Xb[(size_t)i*ND + l*4];
  unsigned word = 0;
  if (l < 32){
    word = ext[((size_t)b*NT + i)*32 + l];
    int js[3] = {i-1, i, i+1};
    #pragma unroll
    for (int qd=0;qd<3;qd++){
      int j = js[qd];
      if (j >= 0 && j < NT && (j>>5) == l) word |= (1u << (j&31));
    }
  }
  float rsum = 0.f; int cnt = 0;
  for (int w=0; w<32; w++){
    unsigned bits = __shfl(word, w);
    while (bits){
      int bit = __ffs(bits) - 1;
      bits &= bits - 1;
      int j = w*32 + bit;
      float4 xj = *(const float4*)&Xb[(size_t)j*ND + l*4];
      float p = xi.x*xj.x + xi.y*xj.y + xi.z*xj.z + xi.w*xj.w;
      #pragma unroll
      for (int off=32; off; off>>=1) p += __shfl_xor(p, off);
      float v = p + ((j==i) ? 1.0f : 0.0f);
      if (l == 0 && cnt < MAXE){
        eidx[(size_t)row*MAXE + cnt] = j;
        eval_[(size_t)row*MAXE + cnt] = v;
      }
      rsum += v; cnt++;
    }
  }
  if (l == 0){ rs[row] = rsum + 1e-6f; ecnt[row] = (cnt < MAXE) ? cnt : MAXE; }
}

// ---------------- K5b: precompute normalized edge weights (once, both layers)
__global__ __launch_bounds__(256) void k_wnorm(const int* __restrict__ eidx,
                                               const float* __restrict__ eval_,
                                               const float* __restrict__ rs,
                                               const int* __restrict__ ecnt,
                                               float* __restrict__ wn){
  int row = blockIdx.x*4 + (threadIdx.x >> 6);
  int lane = threadIdx.x & 63;
  int b = row >> 10;
  int n = ecnt[row];
  float rsi = rs[row];
  if (lane < n){
    int j = eidx[(size_t)row*MAXE + lane];
    float v = eval_[(size_t)row*MAXE + lane];
    wn[(size_t)row*MAXE + lane] = v / sqrtf(rsi * rs[b*NT + j]);
  }
}

// ---------------- K7: FUSED spmm + MFMA dense + bias + elu + LayerNorm ------
// 64 rows x 256 cols/block, 512 threads (8 waves: wy 2 x wx 4). Per kc:
// issue W gld16 (async), then each thread GATHERS its 8-col fp32 segment of
// h = adj_hat @ hin (edges ascending — bit-identical accumulate order and
// f2bf_rn split to the old k_spmm), ds_writes it bf16-split into LDS with
// the XOR swizzle (write chunk = gch ^ (row&7), inverse of the read slot).
// Eliminates the 64 MB hh/hl round-trip and 2 k_spmm launches.
__global__ __launch_bounds__(512) void k_dense2(const float* __restrict__ hin,
                                                const int* __restrict__ eidx,
                                                const float* __restrict__ wn,
                                                const int* __restrict__ ecnt,
                                                const ushort_t* __restrict__ Wh,
                                                const ushort_t* __restrict__ Wl,
                                                const float* __restrict__ bias,
                                                const float* __restrict__ gam,
                                                const float* __restrict__ bet,
                                                float* __restrict__ out){
  __shared__ __align__(16) ushort_t Ahs[64*64];    // 8 KB
  __shared__ __align__(16) ushort_t Als[64*64];    // 8 KB
  __shared__ __align__(16) ushort_t Whs[256*64];   // 32 KB
  __shared__ __align__(16) ushort_t Wls[256*64];   // 32 KB
  __shared__ float sums[64*4];
  __shared__ float sqs[64*4];
  __shared__ float muA[64];
  __shared__ float rsA[64];

  int t = threadIdx.x;
  int lane = t & 63, wave = t >> 6;     // 8 waves
  int wy = wave >> 2, wx = wave & 3;
  int c = lane & 15, q = lane >> 4;
  int lrow = lane >> 3;                 // 0..7
  int sc   = (lane & 7) ^ lrow;         // pre-swizzled source chunk (W stage)
  size_t row0 = (size_t)blockIdx.x * 64;
  int b = (int)(row0 >> 10);            // 1024 % 64 == 0 -> whole block same batch
  const float* Hb = hin + (size_t)b*NT*ND;

  // gather assignment: thread -> (row, 8-col chunk)
  int grow = t >> 3;                    // 0..63 local row
  int gch  = t & 7;                     // chunk 0..7 (8 fp32 cols)
  size_t growg = row0 + grow;           // global row
  int gn = ecnt[growg];
  const int* gei = eidx + growg*MAXE;
  const float* gwe = wn + growg*MAXE;
  int wch = gch ^ (grow & 7);           // swizzled LDS write chunk

  f32x4 acc[2][4];   // [bi (row group)][bj (col group)]
  #pragma unroll
  for (int bi=0;bi<2;bi++)
    #pragma unroll
    for (int bj=0;bj<4;bj++) acc[bi][bj] = {0.f,0.f,0.f,0.f};

  for (int kc=0; kc<4; kc++){
    __syncthreads();                    // previous tile fully consumed
    int koff = kc*64;
    // stage W (async, in flight under the gather below)
    #pragma unroll
    for (int inst=0; inst<4; inst++){
      int r0 = wave*32 + inst*8;
      size_t go = (size_t)(r0 + lrow)*ND + koff + sc*8;
      gld16(Wh + go, &Whs[r0*64]);
      gld16(Wl + go, &Wls[r0*64]);
    }
    // gather A: h[grow][koff + gch*8 .. +8] = sum_e w_e * hin[j_e][...]
    float ga[8] = {0.f,0.f,0.f,0.f,0.f,0.f,0.f,0.f};
    for (int e=0; e<gn; e++){
      int j = gei[e]; float w = gwe[e];
      const float* src = &Hb[(size_t)j*ND + koff + gch*8];
      float4 v0 = *(const float4*)&src[0];
      float4 v1 = *(const float4*)&src[4];
      ga[0] += w*v0.x; ga[1] += w*v0.y; ga[2] += w*v0.z; ga[3] += w*v0.w;
      ga[4] += w*v1.x; ga[5] += w*v1.y; ga[6] += w*v1.z; ga[7] += w*v1.w;
    }
    // split + swizzled ds_write (16B each)
    bf16x8 h8, l8;
    #pragma unroll
    for (int m=0;m<8;m++){
      ushort_t hb = f2bf_rn(ga[m]);
      h8[m] = (short)hb;
      l8[m] = (short)f2bf_rn(ga[m] - bf2f(hb));
    }
    *(bf16x8*)&Ahs[grow*64 + wch*8] = h8;
    *(bf16x8*)&Als[grow*64 + wch*8] = l8;
    __syncthreads();                    // drains vm (W) + lgkm (A writes)

    #pragma unroll
    for (int ks=0; ks<2; ks++){
      bf16x8 ah[2], al[2], wfh[4], wfl[4];
      int slot = (ks*4 + q) ^ (c & 7);
      #pragma unroll
      for (int bi=0;bi<2;bi++){
        int row = wy*32 + bi*16 + c;
        ah[bi] = *(const bf16x8*)&Ahs[row*64 + slot*8];
        al[bi] = *(const bf16x8*)&Als[row*64 + slot*8];
      }
      #pragma unroll
      for (int bj=0;bj<4;bj++){
        int wr = wx*64 + bj*16 + c;
        wfh[bj] = *(const bf16x8*)&Whs[wr*64 + slot*8];
        wfl[bj] = *(const bf16x8*)&Wls[wr*64 + slot*8];
      }
      #pragma unroll
      for (int bi=0;bi<2;bi++)
        #pragma unroll
        for (int bj=0;bj<4;bj++){
          acc[bi][bj] = __builtin_amdgcn_mfma_f32_16x16x32_bf16(ah[bi], wfh[bj], acc[bi][bj], 0, 0, 0);
          acc[bi][bj] = __builtin_amdgcn_mfma_f32_16x16x32_bf16(al[bi], wfh[bj], acc[bi][bj], 0, 0, 0);
          acc[bi][bj] = __builtin_amdgcn_mfma_f32_16x16x32_bf16(ah[bi], wfl[bj], acc[bi][bj], 0, 0, 0);
        }
    }
  }

  // bias + elu (in acc regs)
  float bv[4], gv[4], tv[4];
  #pragma unroll
  for (int bj=0;bj<4;bj++){
    int col = wx*64 + bj*16 + c;
    bv[bj] = bias[col]; gv[bj] = gam[col]; tv[bj] = bet[col];
  }
  #pragma unroll
  for (int bi=0;bi<2;bi++)
    #pragma unroll
    for (int bj=0;bj<4;bj++)
      #pragma unroll
      for (int reg=0;reg<4;reg++){
        float v = acc[bi][bj][reg] + bv[bj];
        acc[bi][bj][reg] = (v > 0.f) ? v : expm1f(v);
      }

  // LN pass 1: mean. Local row = wy*32 + bi*16 + q*4 + reg; col-lane = c.
  #pragma unroll
  for (int bi=0;bi<2;bi++)
    #pragma unroll
    for (int reg=0;reg<4;reg++){
      float s = acc[bi][0][reg] + acc[bi][1][reg] + acc[bi][2][reg] + acc[bi][3][reg];
      #pragma unroll
      for (int st=1; st<16; st<<=1) s += __shfl_xor(s, st);
      if (c == 0) sums[(wy*32 + bi*16 + q*4 + reg)*4 + wx] = s;
    }
  __syncthreads();
  if (t < 64){
    float s = sums[t*4] + sums[t*4+1] + sums[t*4+2] + sums[t*4+3];
    muA[t] = s * (1.0f/ND);
  }
  __syncthreads();
  // LN pass 2: variance
  #pragma unroll
  for (int bi=0;bi<2;bi++)
    #pragma unroll
    for (int reg=0;reg<4;reg++){
      float mu = muA[wy*32 + bi*16 + q*4 + reg];
      float ss = 0.f;
      #pragma unroll
      for (int bj=0;bj<4;bj++){ float d = acc[bi][bj][reg] - mu; ss += d*d; }
      #pragma unroll
      for (int st=1; st<16; st<<=1) ss += __shfl_xor(ss, st);
      if (c == 0) sqs[(wy*32 + bi*16 + q*4 + reg)*4 + wx] = ss;
    }
  __syncthreads();
  if (t < 64){
    float ss = sqs[t*4] + sqs[t*4+1] + sqs[t*4+2] + sqs[t*4+3];
    rsA[t] = rsqrtf(ss * (1.0f/ND) + 1e-5f);
  }
  __syncthreads();
  // affine + store
  #pragma unroll
  for (int bi=0;bi<2;bi++)
    #pragma unroll
    for (int reg=0;reg<4;reg++){
      int row = wy*32 + bi*16 + q*4 + reg;
      float mu = muA[row], rst = rsA[row];
      #pragma unroll
      for (int bj=0;bj<4;bj++){
        float val = (acc[bi][bj][reg] - mu) * rst * gv[bj] + tv[bj];
        out[(row0 + row)*ND + wx*64 + bj*16 + c] = val;
      }
    }
}

// ---------------- host launch ----------------
extern "C" void kernel_launch(void* const* d_in, const int* in_sizes, int n_in,
                              void* d_out, int out_size, void* d_ws, size_t ws_size,
                              hipStream_t stream) {
  (void)in_sizes; (void)n_in; (void)out_size; (void)ws_size;
  const float* x   = (const float*)d_in[0];
  const float* W0  = (const float*)d_in[2];
  const float* b0  = (const float*)d_in[3];
  const float* g0  = (const float*)d_in[4];
  const float* be0 = (const float*)d_in[5];
  const float* W1  = (const float*)d_in[6];
  const float* b1  = (const float*)d_in[7];
  const float* g1  = (const float*)d_in[8];
  const float* be1 = (const float*)d_in[9];
  float* out = (float*)d_out;

  char* wsb = (char*)d_ws;
  // Zone A: xn (permanent)                        [0, 32 MB)
  float* xn = (float*)wsb;
  // Zone B: xh+xl (k_norm -> k_sim), then T (layer-1 output, 32 MB)
  ushort_t* xh = (ushort_t*)(wsb + (size_t)32*1024*1024);
  ushort_t* xl = (ushort_t*)(wsb + (size_t)48*1024*1024);
  float* T = (float*)xh;   // 32 MB, reused after k_sim is done
  // Zone C [64, 98 MB): cand (k_sim -> k_topred, 4 MB, then dead) overlaps
  // ext which only lives from the memset onward.
  char* zc = wsb + (size_t)64*1024*1024;
  unsigned* candS = (unsigned*)zc;                                  // 4 MB
  unsigned* ext   = (unsigned*)zc;                                  // 4 MB
  int*      eidx  = (int*)(zc + (size_t)4*1024*1024);               // 8 MB
  float*    eval_ = (float*)(zc + (size_t)12*1024*1024);            // 8 MB
  float*    rs    = (float*)(zc + (size_t)20*1024*1024);            // 128 KB
  int*      ecnt  = (int*)(zc + (size_t)21*1024*1024);              // 128 KB
  float*    wn    = (float*)(zc + (size_t)22*1024*1024);            // 8 MB
  // Zone D: small persistents                     [98 MB, ...)
  char* zd = wsb + (size_t)98*1024*1024;
  int4* cand4 = (int4*)zd;                            // 512 KB
  int2* top2  = (int2*)(zd + (size_t)512*1024);       // 256 KB
  ushort_t* Wh0 = (ushort_t*)(zd + (size_t)1024*1024);
  ushort_t* Wl0 = Wh0 + 65536;
  ushort_t* Wh1 = Wl0 + 65536;
  ushort_t* Wl1 = Wh1 + 65536;

  k_wsplit<<<256, 256, 0, stream>>>(W0, W1, Wh0, Wl0, Wh1, Wl1);
  k_norm<<<NROWS, 256, 0, stream>>>(x, xn, xh, xl);
  k_sim<<<1152, 256, 0, stream>>>(xh, xl, candS);
  k_topred<<<NROWS/256, 256, 0, stream>>>(candS, cand4);
  k_refine4<<<NROWS, 64, 0, stream>>>(xn, cand4, top2);
  hipMemsetAsync(ext, 0, (size_t)NROWS*32*4, stream);
  k_scatter<<<NROWS/256, 256, 0, stream>>>(top2, ext);
  k_edges<<<NROWS, 64, 0, stream>>>(xn, ext, eidx, eval_, rs, ecnt);
  k_wnorm<<<NROWS/4, 256, 0, stream>>>(eidx, eval_, rs, ecnt, wn);
  // layer 1: fused spmm+dense, x -> T
  k_dense2<<<NROWS/64, 512, 0, stream>>>(x, eidx, wn, ecnt, Wh0, Wl0, b0, g0, be0, T);
  // layer 2: fused spmm+dense, T -> out
  k_dense2<<<NROWS/64, 512, 0, stream>>>(T, eidx, wn, ecnt, Wh1, Wl1, b1, g1, be1, out);
}

// Round 13
// 343.252 us; speedup vs baseline: 1.0789x; 1.0789x over previous
//
#include <hip/hip_runtime.h>
#include <math.h>

#define NB 32
#define NT 1024
#define ND 256
#define NROWS (NB*NT)
#define MAXE 64

typedef __attribute__((ext_vector_type(8))) short bf16x8;
typedef __attribute__((ext_vector_type(4))) float f32x4;
typedef unsigned short ushort_t;
typedef unsigned long long u64;

__device__ inline ushort_t f2bf_rn(float f){
  unsigned u = __float_as_uint(f);
  unsigned r = u + 0x7fffu + ((u >> 16) & 1u);
  return (ushort_t)(r >> 16);
}
__device__ inline float bf2f(ushort_t h){
  return __uint_as_float(((unsigned)h) << 16);
}

// async global->LDS, 16B per lane, dest = ldsbase + lane*16
__device__ inline void gld16(const ushort_t* g, ushort_t* l){
  __builtin_amdgcn_global_load_lds(
      (const __attribute__((address_space(1))) unsigned int*)(g),
      (__attribute__((address_space(3))) unsigned int*)(l),
      16, 0, 0);
}

// orderable key for fp32 (monotone map to unsigned)
__device__ inline unsigned okey(float v){
  unsigned u = __float_as_uint(v);
  return u ^ ((unsigned)((int)u >> 31) | 0x80000000u);
}
// u32 sorted-pair insert / merge (single v_max_u32-class ops)
__device__ inline void ins2u(unsigned &e0, unsigned &e1, unsigned e){
  unsigned mn = e0 > e ? e : e0;
  e0 = e0 > e ? e0 : e;
  e1 = e1 > mn ? e1 : mn;
}
__device__ inline void merge2u(unsigned &e0, unsigned &e1, unsigned r0, unsigned r1){
  unsigned first = e0 > r0 ? e0 : r0;
  unsigned mn    = e0 > r0 ? r0 : e0;
  unsigned mx1   = e1 > r1 ? e1 : r1;
  e0 = first;
  e1 = mn > mx1 ? mn : mx1;
}

// ---------------- K1: row L2-normalize + bf16 split (xh + xl = xn) ----------
__global__ __launch_bounds__(256) void k_norm(const float* __restrict__ x,
                                              float* __restrict__ xn,
                                              ushort_t* __restrict__ xh,
                                              ushort_t* __restrict__ xl){
  int row = blockIdx.x;
  int t = threadIdx.x;
  size_t base = (size_t)row*ND;
  float v = x[base + t];
  float ss = v*v;
  #pragma unroll
  for (int off=32; off; off>>=1) ss += __shfl_xor(ss, off);
  __shared__ float sred[4];
  if ((t & 63) == 0) sred[t>>6] = ss;
  __syncthreads();
  float tot = sred[0] + sred[1] + sred[2] + sred[3];
  float nrm = fmaxf(sqrtf(tot), 1e-12f);
  float res = v / nrm;
  xn[base + t] = res;
  ushort_t hb = f2bf_rn(res);
  float lres = res - bf2f(hb);
  xh[base + t] = hb;
  xl[base + t] = f2bf_rn(lres);
}

// ---------------- Kw: split W into bf16 high/low streams --------------------
__global__ __launch_bounds__(256) void k_wsplit(const float* __restrict__ W0,
                                                const float* __restrict__ W1,
                                                ushort_t* __restrict__ Wh0, ushort_t* __restrict__ Wl0,
                                                ushort_t* __restrict__ Wh1, ushort_t* __restrict__ Wl1){
  int idx = blockIdx.x*256 + threadIdx.x;    // 65536
  float w0 = W0[idx]; ushort_t h0 = f2bf_rn(w0);
  Wh0[idx] = h0; Wl0[idx] = f2bf_rn(w0 - bf2f(h0));
  float w1 = W1[idx]; ushort_t h1 = f2bf_rn(w1);
  Wh1[idx] = h1; Wl1[idx] = f2bf_rn(w1 - bf2f(h1));
}

// ---------------- K2: MFMA sim GEMM, symmetric, FUSED strip-top-2 -----------
// Diagonal tiles (ti==tj) skip B staging entirely (A==B) and read B
// fragments from the A buffers — block-uniform branch.
__global__ __launch_bounds__(256) void k_sim(const ushort_t* __restrict__ xh,
                                             const ushort_t* __restrict__ xl,
                                             unsigned* __restrict__ cand){
  __shared__ __align__(16) ushort_t Ahs[128*64];
  __shared__ __align__(16) ushort_t Als[128*64];
  __shared__ __align__(16) ushort_t Bhs[128*64];
  __shared__ __align__(16) ushort_t Bls[128*64];

  // XCD swizzle: 1152 blocks = 144 contiguous tiles (4 batches) per XCD
  int blk0 = blockIdx.x;
  int blk = (blk0 & 7)*144 + (blk0 >> 3);

  int b = blk / 36;
  int tt = blk % 36;
  int ti = 0, rem = tt;
  while (rem >= 8 - ti){ rem -= 8 - ti; ti++; }
  int tj = ti + rem;                    // ti <= tj
  int i0 = ti*128, j0 = tj*128;
  const bool diag = (ti == tj);

  int t = threadIdx.x;
  int lane = t & 63, wave = t >> 6;
  int wy = wave >> 1, wx = wave & 1;
  int c = lane & 15, q = lane >> 4;
  int lrow = lane >> 3;                 // 0..7 (row within 8-row stage block)
  int sc   = (lane & 7) ^ lrow;         // pre-swizzled source chunk

  const ushort_t* Bh_ = diag ? Ahs : Bhs;
  const ushort_t* Bl_ = diag ? Als : Bls;

  f32x4 acc[4][4];
  #pragma unroll
  for (int bi=0;bi<4;bi++)
    #pragma unroll
    for (int bj=0;bj<4;bj++) acc[bi][bj] = {0.f,0.f,0.f,0.f};

  size_t rowbA = (size_t)(b*NT + i0);
  size_t rowbB = (size_t)(b*NT + j0);
  const ushort_t* Agh = xh + rowbA*ND;
  const ushort_t* Agl = xl + rowbA*ND;
  const ushort_t* Bgh = xh + rowbB*ND;
  const ushort_t* Bgl = xl + rowbB*ND;

  for (int kc=0; kc<4; kc++){
    __syncthreads();                    // previous tile fully consumed
    int koff = kc*64;
    #pragma unroll
    for (int inst=0; inst<4; inst++){
      int r0 = wave*32 + inst*8;        // wave-uniform row base
      size_t go = (size_t)(r0 + lrow)*ND + koff + sc*8;
      gld16(Agh + go, &Ahs[r0*64]);
      gld16(Agl + go, &Als[r0*64]);
      if (!diag){
        gld16(Bgh + go, &Bhs[r0*64]);
        gld16(Bgl + go, &Bls[r0*64]);
      }
    }
    __syncthreads();                    // drains vmcnt before reads

    #pragma unroll
    for (int ks=0; ks<2; ks++){
      bf16x8 ah[4], al[4], bh[4], bl[4];
      int slot = (ks*4 + q) ^ (c & 7);
      #pragma unroll
      for (int bi=0;bi<4;bi++){
        int row = wy*64 + bi*16 + c;
        ah[bi] = *(const bf16x8*)&Ahs[row*64 + slot*8];
        al[bi] = *(const bf16x8*)&Als[row*64 + slot*8];
      }
      #pragma unroll
      for (int bj=0;bj<4;bj++){
        int row = wx*64 + bj*16 + c;
        bh[bj] = *(const bf16x8*)&Bh_[row*64 + slot*8];
        bl[bj] = *(const bf16x8*)&Bl_[row*64 + slot*8];
      }
      #pragma unroll
      for (int bi=0;bi<4;bi++)
        #pragma unroll
        for (int bj=0;bj<4;bj++){
          acc[bi][bj] = __builtin_amdgcn_mfma_f32_16x16x32_bf16(ah[bi], bh[bj], acc[bi][bj], 0, 0, 0);
          acc[bi][bj] = __builtin_amdgcn_mfma_f32_16x16x32_bf16(al[bi], bh[bj], acc[bi][bj], 0, 0, 0);
          acc[bi][bj] = __builtin_amdgcn_mfma_f32_16x16x32_bf16(ah[bi], bl[bj], acc[bi][bj], 0, 0, 0);
        }
    }
  }

  const unsigned KMASK = 0xFFFFFC00u;
  size_t bbase = (size_t)b*NT;
  // epilogue A: direct per-row strip top-2.
  #pragma unroll
  for (int bi=0;bi<4;bi++){
    #pragma unroll
    for (int reg=0;reg<4;reg++){
      int row_l = i0 + wy*64 + bi*16 + q*4 + reg;
      unsigned e0 = 0, e1 = 0;
      #pragma unroll
      for (int bj=0;bj<4;bj++){
        int col_l = j0 + wx*64 + bj*16 + c;
        unsigned e = (okey(acc[bi][bj][reg]) & KMASK) | (unsigned)col_l;
        if (col_l == row_l) e = 0;      // diag suppressed (only diag tiles)
        ins2u(e0, e1, e);
      }
      #pragma unroll
      for (int st=1; st<16; st<<=1)
        merge2u(e0, e1, __shfl_xor(e0, st), __shfl_xor(e1, st));
      if (c == 0){
        u64 pk = ((u64)e1 << 32) | e0;
        *(u64*)&cand[(bbase + row_l)*32 + (size_t)(tj*4 + wx*2)] = pk;
      }
    }
  }
  // epilogue B: mirrored per-column strip top-2 (rows of tile tj, strip ti)
  if (!diag){
    #pragma unroll
    for (int bj=0;bj<4;bj++){
      int mrow = j0 + wx*64 + bj*16 + c;   // mirror row (= column of tile)
      unsigned e0 = 0, e1 = 0;
      #pragma unroll
      for (int bi=0;bi<4;bi++)
        #pragma unroll
        for (int reg=0;reg<4;reg++){
          int mcol = i0 + wy*64 + bi*16 + q*4 + reg;  // mirror col
          unsigned e = (okey(acc[bi][bj][reg]) & KMASK) | (unsigned)mcol;
          ins2u(e0, e1, e);
        }
      #pragma unroll
      for (int st=16; st<64; st<<=1)
        merge2u(e0, e1, __shfl_xor(e0, st), __shfl_xor(e1, st));
      if (q == 0){
        u64 pk = ((u64)e1 << 32) | e0;
        *(u64*)&cand[(bbase + mrow)*32 + (size_t)(ti*4 + wy*2)] = pk;
      }
    }
  }
}

// ---------------- K3: fused top-4-of-strips + fp64 refine + scatter ---------
// Per row: reduce the 32 strip keys to top-4 (same compare logic as the old
// k_topred — all lanes run it on uniform addresses), fp64-refine to top-2,
// and atomicOr the symmetric edge bits directly (old k_scatter folded in).
__global__ __launch_bounds__(64) void k_refine4(const float* __restrict__ xn,
                                               const unsigned* __restrict__ cand,
                                               unsigned* __restrict__ ext){
  int row = blockIdx.x; int b = row >> 10, i = row & 1023;
  int l = threadIdx.x;
  const unsigned* cr = cand + (size_t)row*32;
  unsigned L0=0,L1=0,L2=0,L3=0;
  #pragma unroll
  for (int k=0;k<32;k++){
    unsigned e = cr[k];
    if (e > L0){ L3=L2; L2=L1; L1=L0; L0=e; }
    else if (e > L1){ L3=L2; L2=L1; L1=e; }
    else if (e > L2){ L3=L2; L2=e; }
    else if (e > L3){ L3=e; }
  }
  int cands[4] = {(int)(L0 & 1023u), (int)(L1 & 1023u),
                  (int)(L2 & 1023u), (int)(L3 & 1023u)};
  const float* Xb = xn + (size_t)b*NT*ND;
  float4 xi = *(const float4*)&Xb[(size_t)i*ND + l*4];
  double bv1=-1e30, bv2=-1e30; int bi1=0x7fffffff, bi2=0x7fffffff;
  #pragma unroll
  for (int cq=0;cq<4;cq++){
    int j = cands[cq];
    float4 xj = *(const float4*)&Xb[(size_t)j*ND + l*4];
    double p = (double)xi.x*xj.x + (double)xi.y*xj.y
             + (double)xi.z*xj.z + (double)xi.w*xj.w;
    #pragma unroll
    for (int off=32; off; off>>=1) p += __shfl_xor(p, off);
    if (p > bv1 || (p == bv1 && j < bi1)) { bv2=bv1; bi2=bi1; bv1=p; bi1=j; }
    else if (p > bv2 || (p == bv2 && j < bi2)) { bv2=p; bi2=j; }
  }
  if (l == 0){
    unsigned* eb = ext + (size_t)b*NT*32;
    atomicOr(&eb[(size_t)i*32 + (bi1>>5)], 1u << (bi1&31));
    atomicOr(&eb[(size_t)bi1*32 + (i>>5)], 1u << (i&31));
    atomicOr(&eb[(size_t)i*32 + (bi2>>5)], 1u << (bi2&31));
    atomicOr(&eb[(size_t)bi2*32 + (i>>5)], 1u << (i&31));
  }
}

// ---------------- K5: enumerate edge union, recompute sim values, row sums --
__global__ __launch_bounds__(64) void k_edges(const float* __restrict__ xn,
                                              const unsigned* __restrict__ ext,
                                              int* __restrict__ eidx,
                                              float* __restrict__ eval_,
                                              float* __restrict__ rs,
                                              int* __restrict__ ecnt){
  int row = blockIdx.x; int b = row >> 10, i = row & 1023;
  int l = threadIdx.x;
  const float* Xb = xn + (size_t)b*NT*ND;
  float4 xi = *(const float4*)&Xb[(size_t)i*ND + l*4];
  unsigned word = 0;
  if (l < 32){
    word = ext[((size_t)b*NT + i)*32 + l];
    int js[3] = {i-1, i, i+1};
    #pragma unroll
    for (int qd=0;qd<3;qd++){
      int j = js[qd];
      if (j >= 0 && j < NT && (j>>5) == l) word |= (1u << (j&31));
    }
  }
  float rsum = 0.f; int cnt = 0;
  for (int w=0; w<32; w++){
    unsigned bits = __shfl(word, w);
    while (bits){
      int bit = __ffs(bits) - 1;
      bits &= bits - 1;
      int j = w*32 + bit;
      float4 xj = *(const float4*)&Xb[(size_t)j*ND + l*4];
      float p = xi.x*xj.x + xi.y*xj.y + xi.z*xj.z + xi.w*xj.w;
      #pragma unroll
      for (int off=32; off; off>>=1) p += __shfl_xor(p, off);
      float v = p + ((j==i) ? 1.0f : 0.0f);
      if (l == 0 && cnt < MAXE){
        eidx[(size_t)row*MAXE + cnt] = j;
        eval_[(size_t)row*MAXE + cnt] = v;
      }
      rsum += v; cnt++;
    }
  }
  if (l == 0){ rs[row] = rsum + 1e-6f; ecnt[row] = (cnt < MAXE) ? cnt : MAXE; }
}

// ---------------- K5b: precompute normalized edge weights (once, both layers)
__global__ __launch_bounds__(256) void k_wnorm(const int* __restrict__ eidx,
                                               const float* __restrict__ eval_,
                                               const float* __restrict__ rs,
                                               const int* __restrict__ ecnt,
                                               float* __restrict__ wn){
  int row = blockIdx.x*4 + (threadIdx.x >> 6);
  int lane = threadIdx.x & 63;
  int b = row >> 10;
  int n = ecnt[row];
  float rsi = rs[row];
  if (lane < n){
    int j = eidx[(size_t)row*MAXE + lane];
    float v = eval_[(size_t)row*MAXE + lane];
    wn[(size_t)row*MAXE + lane] = v / sqrtf(rsi * rs[b*NT + j]);
  }
}

// ---------------- K6: sparse aggregation, bf16-split output (hh + hl) -------
__global__ __launch_bounds__(256) void k_spmm(const float* __restrict__ hin,
                                              const int* __restrict__ eidx,
                                              const float* __restrict__ wn,
                                              const int* __restrict__ ecnt,
                                              ushort_t* __restrict__ Hh,
                                              ushort_t* __restrict__ Hl){
  int row = blockIdx.x*4 + (threadIdx.x >> 6);
  int lane = threadIdx.x & 63;
  int b = row >> 10;
  const float* Hb = hin + (size_t)b*NT*ND;
  int n = ecnt[row];
  const int* ei = eidx + (size_t)row*MAXE;
  const float* we = wn + (size_t)row*MAXE;
  float4 acc = {0.f,0.f,0.f,0.f};
  int e = 0;
  for (; e+2 <= n; e += 2){
    int j0 = ei[e],   j1 = ei[e+1];
    float w0 = we[e], w1 = we[e+1];
    float4 v0 = *(const float4*)&Hb[(size_t)j0*ND + lane*4];
    float4 v1 = *(const float4*)&Hb[(size_t)j1*ND + lane*4];
    acc.x += w0*v0.x; acc.y += w0*v0.y; acc.z += w0*v0.z; acc.w += w0*v0.w;
    acc.x += w1*v1.x; acc.y += w1*v1.y; acc.z += w1*v1.z; acc.w += w1*v1.w;
  }
  if (e < n){
    int j0 = ei[e]; float w0 = we[e];
    float4 v0 = *(const float4*)&Hb[(size_t)j0*ND + lane*4];
    acc.x += w0*v0.x; acc.y += w0*v0.y; acc.z += w0*v0.z; acc.w += w0*v0.w;
  }
  float av[4] = {acc.x, acc.y, acc.z, acc.w};
  u64 ph = 0, pl = 0;
  #pragma unroll
  for (int m=0;m<4;m++){
    ushort_t hb = f2bf_rn(av[m]);
    ushort_t lb = f2bf_rn(av[m] - bf2f(hb));
    ph |= (u64)hb << (16*m);
    pl |= (u64)lb << (16*m);
  }
  *(u64*)&Hh[(size_t)row*ND + lane*4] = ph;
  *(u64*)&Hl[(size_t)row*ND + lane*4] = pl;
}

// ---------------- K7: MFMA dense h@W^T + bias + elu + LayerNorm -------------
// 64 rows x 256 cols/block, 512 threads (8 waves: wy 2 x wx 4). W staged in
// LDS per kc (coalesced gld16, XOR swizzle), shared by all 8 waves.
__global__ __launch_bounds__(512) void k_dense2(const ushort_t* __restrict__ Hh,
                                                const ushort_t* __restrict__ Hl,
                                                const ushort_t* __restrict__ Wh,
                                                const ushort_t* __restrict__ Wl,
                                                const float* __restrict__ bias,
                                                const float* __restrict__ gam,
                                                const float* __restrict__ bet,
                                                float* __restrict__ out){
  __shared__ __align__(16) ushort_t Ahs[64*64];    // 8 KB
  __shared__ __align__(16) ushort_t Als[64*64];    // 8 KB
  __shared__ __align__(16) ushort_t Whs[256*64];   // 32 KB
  __shared__ __align__(16) ushort_t Wls[256*64];   // 32 KB
  __shared__ float sums[64*4];
  __shared__ float sqs[64*4];
  __shared__ float muA[64];
  __shared__ float rsA[64];

  int t = threadIdx.x;
  int lane = t & 63, wave = t >> 6;     // 8 waves
  int wy = wave >> 2, wx = wave & 3;
  int c = lane & 15, q = lane >> 4;
  int lrow = lane >> 3;                 // 0..7
  int sc   = (lane & 7) ^ lrow;         // pre-swizzled source chunk
  size_t row0 = (size_t)blockIdx.x * 64;

  const ushort_t* Hhb = Hh + row0*ND;
  const ushort_t* Hlb = Hl + row0*ND;

  f32x4 acc[2][4];   // [bi (row group)][bj (col group)]
  #pragma unroll
  for (int bi=0;bi<2;bi++)
    #pragma unroll
    for (int bj=0;bj<4;bj++) acc[bi][bj] = {0.f,0.f,0.f,0.f};

  for (int kc=0; kc<4; kc++){
    __syncthreads();                    // previous tile fully consumed
    int koff = kc*64;
    { // stage A: 64 rows x 64 K, 8 rows per wave (1 gld16 per stream)
      int r0 = wave*8;
      size_t go = (size_t)(r0 + lrow)*ND + koff + sc*8;
      gld16(Hhb + go, &Ahs[r0*64]);
      gld16(Hlb + go, &Als[r0*64]);
    }
    // stage W: 256 rows x 64 K, 32 rows per wave (4 gld16 per stream)
    #pragma unroll
    for (int inst=0; inst<4; inst++){
      int r0 = wave*32 + inst*8;
      size_t go = (size_t)(r0 + lrow)*ND + koff + sc*8;
      gld16(Wh + go, &Whs[r0*64]);
      gld16(Wl + go, &Wls[r0*64]);
    }
    __syncthreads();                    // drains vmcnt before reads

    #pragma unroll
    for (int ks=0; ks<2; ks++){
      bf16x8 ah[2], al[2], wfh[4], wfl[4];
      int slot = (ks*4 + q) ^ (c & 7);
      #pragma unroll
      for (int bi=0;bi<2;bi++){
        int row = wy*32 + bi*16 + c;
        ah[bi] = *(const bf16x8*)&Ahs[row*64 + slot*8];
        al[bi] = *(const bf16x8*)&Als[row*64 + slot*8];
      }
      #pragma unroll
      for (int bj=0;bj<4;bj++){
        int wr = wx*64 + bj*16 + c;
        wfh[bj] = *(const bf16x8*)&Whs[wr*64 + slot*8];
        wfl[bj] = *(const bf16x8*)&Wls[wr*64 + slot*8];
      }
      #pragma unroll
      for (int bi=0;bi<2;bi++)
        #pragma unroll
        for (int bj=0;bj<4;bj++){
          acc[bi][bj] = __builtin_amdgcn_mfma_f32_16x16x32_bf16(ah[bi], wfh[bj], acc[bi][bj], 0, 0, 0);
          acc[bi][bj] = __builtin_amdgcn_mfma_f32_16x16x32_bf16(al[bi], wfh[bj], acc[bi][bj], 0, 0, 0);
          acc[bi][bj] = __builtin_amdgcn_mfma_f32_16x16x32_bf16(ah[bi], wfl[bj], acc[bi][bj], 0, 0, 0);
        }
    }
  }

  // bias + elu (in acc regs)
  float bv[4], gv[4], tv[4];
  #pragma unroll
  for (int bj=0;bj<4;bj++){
    int col = wx*64 + bj*16 + c;
    bv[bj] = bias[col]; gv[bj] = gam[col]; tv[bj] = bet[col];
  }
  #pragma unroll
  for (int bi=0;bi<2;bi++)
    #pragma unroll
    for (int bj=0;bj<4;bj++)
      #pragma unroll
      for (int reg=0;reg<4;reg++){
        float v = acc[bi][bj][reg] + bv[bj];
        acc[bi][bj][reg] = (v > 0.f) ? v : expm1f(v);
      }

  // LN pass 1: mean. Local row = wy*32 + bi*16 + q*4 + reg; col-lane = c.
  #pragma unroll
  for (int bi=0;bi<2;bi++)
    #pragma unroll
    for (int reg=0;reg<4;reg++){
      float s = acc[bi][0][reg] + acc[bi][1][reg] + acc[bi][2][reg] + acc[bi][3][reg];
      #pragma unroll
      for (int st=1; st<16; st<<=1) s += __shfl_xor(s, st);
      if (c == 0) sums[(wy*32 + bi*16 + q*4 + reg)*4 + wx] = s;
    }
  __syncthreads();
  if (t < 64){
    float s = sums[t*4] + sums[t*4+1] + sums[t*4+2] + sums[t*4+3];
    muA[t] = s * (1.0f/ND);
  }
  __syncthreads();
  // LN pass 2: variance
  #pragma unroll
  for (int bi=0;bi<2;bi++)
    #pragma unroll
    for (int reg=0;reg<4;reg++){
      float mu = muA[wy*32 + bi*16 + q*4 + reg];
      float ss = 0.f;
      #pragma unroll
      for (int bj=0;bj<4;bj++){ float d = acc[bi][bj][reg] - mu; ss += d*d; }
      #pragma unroll
      for (int st=1; st<16; st<<=1) ss += __shfl_xor(ss, st);
      if (c == 0) sqs[(wy*32 + bi*16 + q*4 + reg)*4 + wx] = ss;
    }
  __syncthreads();
  if (t < 64){
    float ss = sqs[t*4] + sqs[t*4+1] + sqs[t*4+2] + sqs[t*4+3];
    rsA[t] = rsqrtf(ss * (1.0f/ND) + 1e-5f);
  }
  __syncthreads();
  // affine + store
  #pragma unroll
  for (int bi=0;bi<2;bi++)
    #pragma unroll
    for (int reg=0;reg<4;reg++){
      int row = wy*32 + bi*16 + q*4 + reg;
      float mu = muA[row], rst = rsA[row];
      #pragma unroll
      for (int bj=0;bj<4;bj++){
        float val = (acc[bi][bj][reg] - mu) * rst * gv[bj] + tv[bj];
        out[(row0 + row)*ND + wx*64 + bj*16 + c] = val;
      }
    }
}

// ---------------- host launch ----------------
extern "C" void kernel_launch(void* const* d_in, const int* in_sizes, int n_in,
                              void* d_out, int out_size, void* d_ws, size_t ws_size,
                              hipStream_t stream) {
  (void)in_sizes; (void)n_in; (void)out_size; (void)ws_size;
  const float* x   = (const float*)d_in[0];
  const float* W0  = (const float*)d_in[2];
  const float* b0  = (const float*)d_in[3];
  const float* g0  = (const float*)d_in[4];
  const float* be0 = (const float*)d_in[5];
  const float* W1  = (const float*)d_in[6];
  const float* b1  = (const float*)d_in[7];
  const float* g1  = (const float*)d_in[8];
  const float* be1 = (const float*)d_in[9];
  float* out = (float*)d_out;

  char* wsb = (char*)d_ws;
  // Zone A: xn (permanent)                        [0, 32 MB)
  float* xn = (float*)wsb;
  // Zone B: xh+xl (k_norm -> k_sim), then hh/hl   [32 MB, 64 MB)
  ushort_t* xh = (ushort_t*)(wsb + (size_t)32*1024*1024);
  ushort_t* xl = (ushort_t*)(wsb + (size_t)48*1024*1024);
  ushort_t* hh = xh;   // 16 MB, reused after k_sim is done
  ushort_t* hl = xl;   // 16 MB
  // Zone C [64, 98 MB): ext/eidx/eval/rs/ecnt/wn; candS parked at +30 MB so
  // it does NOT alias ext (memset now precedes the fused refine).
  char* zc = wsb + (size_t)64*1024*1024;
  unsigned* ext   = (unsigned*)zc;                                  // 4 MB
  int*      eidx  = (int*)(zc + (size_t)4*1024*1024);               // 8 MB
  float*    eval_ = (float*)(zc + (size_t)12*1024*1024);            // 8 MB
  float*    rs    = (float*)(zc + (size_t)20*1024*1024);            // 128 KB
  int*      ecnt  = (int*)(zc + (size_t)21*1024*1024);              // 128 KB
  float*    wn    = (float*)(zc + (size_t)22*1024*1024);            // 8 MB
  unsigned* candS = (unsigned*)(zc + (size_t)30*1024*1024);         // 4 MB
  // Zone D: small persistents                     [98 MB, ...)
  char* zd = wsb + (size_t)98*1024*1024;
  ushort_t* Wh0 = (ushort_t*)zd;
  ushort_t* Wl0 = Wh0 + 65536;
  ushort_t* Wh1 = Wl0 + 65536;
  ushort_t* Wl1 = Wh1 + 65536;

  k_wsplit<<<256, 256, 0, stream>>>(W0, W1, Wh0, Wl0, Wh1, Wl1);
  k_norm<<<NROWS, 256, 0, stream>>>(x, xn, xh, xl);
  k_sim<<<1152, 256, 0, stream>>>(xh, xl, candS);
  hipMemsetAsync(ext, 0, (size_t)NROWS*32*4, stream);
  k_refine4<<<NROWS, 64, 0, stream>>>(xn, candS, ext);
  k_edges<<<NROWS, 64, 0, stream>>>(xn, ext, eidx, eval_, rs, ecnt);
  k_wnorm<<<NROWS/4, 256, 0, stream>>>(eidx, eval_, rs, ecnt, wn);
  // layer 1
  k_spmm<<<NROWS/4, 256, 0, stream>>>(x, eidx, wn, ecnt, hh, hl);
  k_dense2<<<NROWS/64, 512, 0, stream>>>(hh, hl, Wh0, Wl0, b0, g0, be0, out);
  // layer 2
  k_spmm<<<NROWS/4, 256, 0, stream>>>(out, eidx, wn, ecnt, hh, hl);
  k_dense2<<<NROWS/64, 512, 0, stream>>>(hh, hl, Wh1, Wl1, b1, g1, be1, out);
}